// Round 13
// baseline (73.887 us; speedup 1.0000x reference)
//
#include <hip/hip_runtime.h>

typedef __attribute__((ext_vector_type(8))) short bf16x8;
typedef __attribute__((ext_vector_type(4))) float f32x4;
typedef __attribute__((ext_vector_type(2))) long long2v;
typedef unsigned int u32;
typedef unsigned long long u64;

#define LOG2E 1.44269504088896f

__device__ __forceinline__ short f2bf(float f) {
    union { float f; unsigned u; } v; v.f = f;
    unsigned r = v.u + 0x7fffu + ((v.u >> 16) & 1u);
    return (short)(r >> 16);
}

// float -> OCP e4m3fn byte (RNE, saturate to 448)
__device__ __forceinline__ u32 f2e4m3(float f) {
    u32 u = __float_as_uint(f);
    u32 sgn = (u >> 24) & 0x80u;
    u32 mag = u & 0x7fffffffu;
    if (mag >= 0x43E00000u) return sgn | 0x7Eu;
    if (mag < 0x3C800000u) {
        u32 q = (u32)(__uint_as_float(mag) * 512.0f + 0.5f);
        return sgn | q;
    }
    u32 r = mag + 0x0007FFFFu + ((mag >> 20) & 1u);
    u32 e8 = ((r >> 23) - 120u) & 0xFu;
    u32 m3 = (r >> 20) & 7u;
    return sgn | (e8 << 3) | m3;
}

__device__ __forceinline__ long pack8_e4m3(float4 a, float4 b) {
    u32 lo = f2e4m3(a.x) | (f2e4m3(a.y) << 8) | (f2e4m3(a.z) << 16) | (f2e4m3(a.w) << 24);
    u32 hi = f2e4m3(b.x) | (f2e4m3(b.y) << 8) | (f2e4m3(b.z) << 16) | (f2e4m3(b.w) << 24);
    return (long)(((u64)hi << 32) | lo);
}

#if __has_builtin(__builtin_amdgcn_exp2f)
#define EXP2(x) __builtin_amdgcn_exp2f(x)
#else
#define EXP2(x) __builtin_exp2f(x)
#endif

__device__ __forceinline__ u32 pack_bf16_trunc(float lo, float hi) {
#if __has_builtin(__builtin_amdgcn_perm)
    return __builtin_amdgcn_perm(__float_as_uint(hi), __float_as_uint(lo), 0x07060302u);
#else
    return (__float_as_uint(hi) & 0xFFFF0000u) | (__float_as_uint(lo) >> 16);
#endif
}

__device__ __forceinline__ void gload16(const void* g, void* l) {
    __builtin_amdgcn_global_load_lds(
        (const __attribute__((address_space(1))) void*)g,
        (__attribute__((address_space(3))) void*)l, 16, 0, 0);
}

// ---------------- prep ----------------
// bid 0..255  : per-center scalar tables, permuted slot ((c*2+h)*4+g)*4+j for
//               center m = c*32+8g+4h+j (r9-verified): nscs=-s*||c||^2*L, ts=2s*L
// bid 256..319: centers -> cfrag8, 16B slots [c][ks][lane] = {A0(h=0), A1(h=1)}:
//               A_h from center m = c*32+8*(l15>>2)+4*h+(l15&3), k = ks*32+(l>>4)*8
// bid 320..383: W -> wfrag (bf16) PV B-frag [c][ot][lane]: o=ot*16+l15, k=c*32+(l>>4)*8
__global__ __launch_bounds__(256) void rbf_prep(
    const float* __restrict__ centers, const float* __restrict__ sigmas,
    const float* __restrict__ W,
    char* __restrict__ cfrag8, short* __restrict__ wfrag,
    float* __restrict__ nscsp, float* __restrict__ tsp)
{
    const int tid = threadIdx.x;
    const int bid = blockIdx.x;
    if (bid < 256) {
        const int lane = tid & 63, w = tid >> 6;
        const int m = bid * 4 + w;
        const float4 v = ((const float4*)(centers + (size_t)m * 256))[lane];
        float s = v.x*v.x + v.y*v.y + v.z*v.z + v.w*v.w;
        #pragma unroll
        for (int off = 32; off >= 1; off >>= 1) s += __shfl_xor(s, off, 64);
        if (lane == 0) {
            const float sg = sigmas[m];
            const int c = m >> 5, w5 = m & 31;
            const int g = w5 >> 3, r = w5 & 7, h = r >> 2, j = r & 3;
            const int slot = ((c * 2 + h) * 4 + g) * 4 + j;
            nscsp[slot] = -sg * s * LOG2E;
            tsp[slot]   = 2.0f * sg * LOG2E;
        }
    } else if (bid < 320) {
        const int s = (bid - 256) * 256 + tid;               // 0..16383 (16B slots)
        const int c = s >> 9, ks = (s >> 6) & 7, lane = s & 63;
        const int l15 = lane & 15;
        const int k = ks * 32 + (lane >> 4) * 8;
        long2v t;
        #pragma unroll
        for (int h = 0; h < 2; ++h) {
            const int m = c * 32 + 8 * (l15 >> 2) + 4 * h + (l15 & 3);
            const float4 a = *(const float4*)(centers + (size_t)m * 256 + k);
            const float4 b = *(const float4*)(centers + (size_t)m * 256 + k + 4);
            t[h] = pack8_e4m3(a, b);
        }
        *(long2v*)(cfrag8 + (size_t)s * 16) = t;
    } else {
        const int s = (bid - 320) * 256 + tid;               // 0..16383
        const int c = s >> 9, ot = (s >> 6) & 7, lane = s & 63;
        const int o = ot * 16 + (lane & 15);
        const int k = c * 32 + (lane >> 4) * 8;
        const float4 a = *(const float4*)(W + (size_t)o * 1024 + k);
        const float4 b = *(const float4*)(W + (size_t)o * 1024 + k + 4);
        bf16x8 t;
        t[0]=f2bf(a.x); t[1]=f2bf(a.y); t[2]=f2bf(a.z); t[3]=f2bf(a.w);
        t[4]=f2bf(b.x); t[5]=f2bf(b.y); t[6]=f2bf(b.z); t[7]=f2bf(b.w);
        ((bf16x8*)wfrag)[s] = t;
    }
}

// ---------------- main: r9 occupancy x r11/r12 clean pipeline ----------------
// 1024 blocks x 256 threads, 16 rows/wave, LDS 40KB -> 4 blocks/CU (16 waves/CU,
// 4 independent barrier domains). In-loop vmem = STAGE DMAs only (tables in LDS,
// 2-table fold). Ring-2, __syncthreads per chunk (drain covered by block stagger).
// S-phase reads both A-halves in one ds_read_b128.
__global__ __launch_bounds__(256, 4) void rbf_main(
    const float* __restrict__ x, const float* __restrict__ bvec,
    const char* __restrict__ cfrag8, const short* __restrict__ wfrag,
    const float* __restrict__ nscsp, const float* __restrict__ tsp,
    float* __restrict__ out)
{
    __shared__ char   Cb8[2][8192];   // [ks][lane]16B: ks*1024 + lane*16
    __shared__ short  Wb[2][4096];    // [ot][lane]16B: ot*1024B + lane*16B
    __shared__ float4 Tls[512];       // 8 KB: [0..255]=nscs, [256..511]=ts (permuted)

    const int tid = threadIdx.x;
    const int lane = tid & 63;
    const int l15 = lane & 15;
    const int g4 = lane >> 4;
    const int w = tid >> 6;                   // 0..3
    const int qb = blockIdx.x * 64 + w * 16;  // 16 rows per wave

#define STAGE(ci, P) do {                                                          \
        const char* _cs = cfrag8 + (size_t)(ci) * 8192 + w * 2048 + lane * 16;     \
        gload16(_cs,        &Cb8[(P)][w * 2048]);                                  \
        gload16(_cs + 1024, &Cb8[(P)][w * 2048 + 1024]);                           \
        const char* _ws = (const char*)wfrag + (size_t)(ci) * 8192 + w * 2048 + lane * 16; \
        gload16(_ws,        (char*)&Wb[(P)][0] + w * 2048);                        \
        gload16(_ws + 1024, (char*)&Wb[(P)][0] + w * 2048 + 1024);                 \
    } while (0)

    // ---- prologue: stage chunk 0; tables -> LDS; X -> fp8 regs ----
    STAGE(0, 0);

    Tls[tid]       = ((const float4*)nscsp)[tid];
    Tls[256 + tid] = ((const float4*)tsp)[tid];

    long xq8[8];
    const float* xr = x + (size_t)(qb + l15) * 256 + g4 * 8;
    float ss = 0.f;
    #pragma unroll
    for (int ks = 0; ks < 8; ++ks) {
        const float4 a = *(const float4*)(xr + ks * 32);
        const float4 b = *(const float4*)(xr + ks * 32 + 4);
        ss += a.x*a.x + a.y*a.y + a.z*a.z + a.w*a.w
            + b.x*b.x + b.y*b.y + b.z*b.z + b.w*b.w;
        xq8[ks] = pack8_e4m3(a, b);
    }
    ss += __shfl_xor(ss, 16, 64);
    ss += __shfl_xor(ss, 32, 64);
    const float hxs = 0.5f * ss;   // arg = ts*(S - xs/2) + nscs

    f32x4 acc[8];
    #pragma unroll
    for (int ot = 0; ot < 8; ++ot) acc[ot] = (f32x4){0.f, 0.f, 0.f, 0.f};

    __syncthreads();   // chunk-0 DMA + table writes + X loads drained

    int buf = 0;
    for (int c = 0; c < 32; ++c) {
        if (c < 31) STAGE(c + 1, buf ^ 1);

        // ---- S: 8 x ds_read_b128 -> {A0,A1}; 2 fp8 MFMA chains ----
        f32x4 s0 = (f32x4){0.f,0.f,0.f,0.f}, s1 = s0;
        {
            const char* cb = &Cb8[buf][0] + (size_t)lane * 16;
            #pragma unroll
            for (int ks = 0; ks < 8; ++ks) {
                const long2v A = *(const long2v*)(cb + ks * 1024);
                s0 = __builtin_amdgcn_mfma_f32_16x16x32_fp8_fp8(A[0], xq8[ks], s0, 0, 0, 0);
                s1 = __builtin_amdgcn_mfma_f32_16x16x32_fp8_fp8(A[1], xq8[ks], s1, 0, 0, 0);
            }
        }

        // ---- phi = exp2(ts*(S - xs/2) + nscs); tables from LDS ----
        const int base0 = (c * 2 + 0) * 4 + g4;
        const int base1 = (c * 2 + 1) * 4 + g4;
        const float4 q0 = Tls[base0];
        const float4 t0 = Tls[256 + base0];
        const float4 q1 = Tls[base1];
        const float4 t1 = Tls[256 + base1];
        const float* q0p = (const float*)&q0; const float* t0p = (const float*)&t0;
        const float* q1p = (const float*)&q1; const float* t1p = (const float*)&t1;
        float p0[4], p1[4];
        #pragma unroll
        for (int j = 0; j < 4; ++j) {
            p0[j] = EXP2(fmaf(t0p[j], s0[j] - hxs, q0p[j]));
            p1[j] = EXP2(fmaf(t1p[j], s1[j] - hxs, q1p[j]));
        }
        union { u32 u[4]; bf16x8 v; } pa;
        pa.u[0] = pack_bf16_trunc(p0[0], p0[1]);
        pa.u[1] = pack_bf16_trunc(p0[2], p0[3]);
        pa.u[2] = pack_bf16_trunc(p1[0], p1[1]);
        pa.u[3] = pack_bf16_trunc(p1[2], p1[3]);

        // ---- PV: 8 bf16 MFMAs, W-frags from LDS ----
        {
            const bf16x8* wbl = (const bf16x8*)&Wb[buf][0] + lane;
            #pragma unroll
            for (int ot = 0; ot < 8; ++ot)
                acc[ot] = __builtin_amdgcn_mfma_f32_16x16x32_bf16(pa.v, wbl[ot * 64], acc[ot], 0, 0, 0);
        }

        __syncthreads();   // drains next-chunk DMA; all waves done with buf
        buf ^= 1;
    }

    // ---- epilogue: D layout col=l15 (o-sub), row=g4*4+jr (q-sub) ----
    #pragma unroll
    for (int jr = 0; jr < 4; ++jr) {
        const int q = qb + g4 * 4 + jr;
        #pragma unroll
        for (int ot = 0; ot < 8; ++ot)
            out[(size_t)q * 128 + ot * 16 + l15] = acc[ot][jr] + bvec[ot * 16 + l15];
    }
#undef STAGE
}

extern "C" void kernel_launch(void* const* d_in, const int* in_sizes, int n_in,
                              void* d_out, int out_size, void* d_ws, size_t ws_size,
                              hipStream_t stream) {
    (void)in_sizes; (void)n_in; (void)out_size; (void)ws_size;
    const float* x       = (const float*)d_in[0];
    const float* centers = (const float*)d_in[1];
    const float* sigmas  = (const float*)d_in[2];
    const float* W       = (const float*)d_in[3];
    const float* b       = (const float*)d_in[4];
    float* out = (float*)d_out;

    char*  cfrag8 = (char*)d_ws;                     // 16384 slots * 16B = 256 KB
    short* wfrag  = (short*)(cfrag8 + 16384 * 16);   // 16384 slots * 16B = 256 KB
    float* nscsp  = (float*)(wfrag + 16384 * 8);     // 4 KB
    float* tsp    = nscsp + 1024;                    // 4 KB

    rbf_prep<<<384, 256, 0, stream>>>(centers, sigmas, W, cfrag8, wfrag, nscsp, tsp);
    rbf_main<<<1024, 256, 0, stream>>>(x, b, cfrag8, wfrag, nscsp, tsp, out);
}

// Round 14
// 70.063 us; speedup vs baseline: 1.0546x; 1.0546x over previous
//
#include <hip/hip_runtime.h>

typedef __attribute__((ext_vector_type(8))) short bf16x8;
typedef __attribute__((ext_vector_type(4))) float f32x4;
typedef __attribute__((ext_vector_type(2))) long long2v;
typedef unsigned int u32;
typedef unsigned long long u64;

#define LOG2E 1.44269504088896f

__device__ __forceinline__ short f2bf(float f) {
    union { float f; unsigned u; } v; v.f = f;
    unsigned r = v.u + 0x7fffu + ((v.u >> 16) & 1u);
    return (short)(r >> 16);
}

// float -> OCP e4m3fn byte (RNE, saturate to 448)
__device__ __forceinline__ u32 f2e4m3(float f) {
    u32 u = __float_as_uint(f);
    u32 sgn = (u >> 24) & 0x80u;
    u32 mag = u & 0x7fffffffu;
    if (mag >= 0x43E00000u) return sgn | 0x7Eu;
    if (mag < 0x3C800000u) {
        u32 q = (u32)(__uint_as_float(mag) * 512.0f + 0.5f);
        return sgn | q;
    }
    u32 r = mag + 0x0007FFFFu + ((mag >> 20) & 1u);
    u32 e8 = ((r >> 23) - 120u) & 0xFu;
    u32 m3 = (r >> 20) & 7u;
    return sgn | (e8 << 3) | m3;
}

__device__ __forceinline__ long pack8_e4m3(float4 a, float4 b) {
    u32 lo = f2e4m3(a.x) | (f2e4m3(a.y) << 8) | (f2e4m3(a.z) << 16) | (f2e4m3(a.w) << 24);
    u32 hi = f2e4m3(b.x) | (f2e4m3(b.y) << 8) | (f2e4m3(b.z) << 16) | (f2e4m3(b.w) << 24);
    return (long)(((u64)hi << 32) | lo);
}

#if __has_builtin(__builtin_amdgcn_exp2f)
#define EXP2(x) __builtin_amdgcn_exp2f(x)
#else
#define EXP2(x) __builtin_exp2f(x)
#endif

__device__ __forceinline__ u32 pack_bf16_trunc(float lo, float hi) {
#if __has_builtin(__builtin_amdgcn_perm)
    return __builtin_amdgcn_perm(__float_as_uint(hi), __float_as_uint(lo), 0x07060302u);
#else
    return (__float_as_uint(hi) & 0xFFFF0000u) | (__float_as_uint(lo) >> 16);
#endif
}

__device__ __forceinline__ void gload16(const void* g, void* l) {
    __builtin_amdgcn_global_load_lds(
        (const __attribute__((address_space(1))) void*)g,
        (__attribute__((address_space(3))) void*)l, 16, 0, 0);
}

// ---------------- prep (verbatim r13; absmax 0.0 verified) ----------------
// bid 0..255  : 2-fold tables, permuted slot ((c*2+h)*4+g)*4+j for center
//               m = c*32+8g+4h+j: nscs=-s*||c||^2*L, ts=2s*L
// bid 256..319: centers -> cfrag8, 16B slots [c][ks][lane] = {A0(h=0), A1(h=1)}
// bid 320..383: W -> wfrag (bf16) PV B-frag [c][ot][lane]: o=ot*16+l15, k=c*32+(l>>4)*8
__global__ __launch_bounds__(256) void rbf_prep(
    const float* __restrict__ centers, const float* __restrict__ sigmas,
    const float* __restrict__ W,
    char* __restrict__ cfrag8, short* __restrict__ wfrag,
    float* __restrict__ nscsp, float* __restrict__ tsp)
{
    const int tid = threadIdx.x;
    const int bid = blockIdx.x;
    if (bid < 256) {
        const int lane = tid & 63, w = tid >> 6;
        const int m = bid * 4 + w;
        const float4 v = ((const float4*)(centers + (size_t)m * 256))[lane];
        float s = v.x*v.x + v.y*v.y + v.z*v.z + v.w*v.w;
        #pragma unroll
        for (int off = 32; off >= 1; off >>= 1) s += __shfl_xor(s, off, 64);
        if (lane == 0) {
            const float sg = sigmas[m];
            const int c = m >> 5, w5 = m & 31;
            const int g = w5 >> 3, r = w5 & 7, h = r >> 2, j = r & 3;
            const int slot = ((c * 2 + h) * 4 + g) * 4 + j;
            nscsp[slot] = -sg * s * LOG2E;
            tsp[slot]   = 2.0f * sg * LOG2E;
        }
    } else if (bid < 320) {
        const int s = (bid - 256) * 256 + tid;               // 0..16383 (16B slots)
        const int c = s >> 9, ks = (s >> 6) & 7, lane = s & 63;
        const int l15 = lane & 15;
        const int k = ks * 32 + (lane >> 4) * 8;
        long2v t;
        #pragma unroll
        for (int h = 0; h < 2; ++h) {
            const int m = c * 32 + 8 * (l15 >> 2) + 4 * h + (l15 & 3);
            const float4 a = *(const float4*)(centers + (size_t)m * 256 + k);
            const float4 b = *(const float4*)(centers + (size_t)m * 256 + k + 4);
            t[h] = pack8_e4m3(a, b);
        }
        *(long2v*)(cfrag8 + (size_t)s * 16) = t;
    } else {
        const int s = (bid - 320) * 256 + tid;               // 0..16383
        const int c = s >> 9, ot = (s >> 6) & 7, lane = s & 63;
        const int o = ot * 16 + (lane & 15);
        const int k = c * 32 + (lane >> 4) * 8;
        const float4 a = *(const float4*)(W + (size_t)o * 1024 + k);
        const float4 b = *(const float4*)(W + (size_t)o * 1024 + k + 4);
        bf16x8 t;
        t[0]=f2bf(a.x); t[1]=f2bf(a.y); t[2]=f2bf(a.z); t[3]=f2bf(a.w);
        t[4]=f2bf(b.x); t[5]=f2bf(b.y); t[6]=f2bf(b.z); t[7]=f2bf(b.w);
        ((bf16x8*)wfrag)[s] = t;
    }
}

// ---------------- main: r12 geometry, W on VMEM, packed-A b128, 2 chunks/barrier ----------------
// 512 blocks x 256 threads (4 waves, 32 rows/wave), 2 blocks/CU. LDS holds only
// the C-ring (4 x 8KB, pair double-buffer) + tables (8KB) = 40KB. W-frags load
// global->regs on the idle VMEM pipe, issued ~600cy ahead (wA at iter top, wB
// after chunk-A's exp); in-order vmcnt retires W without draining STAGE DMAs.
__global__ __launch_bounds__(256, 2) void rbf_main(
    const float* __restrict__ x, const float* __restrict__ bvec,
    const char* __restrict__ cfrag8, const short* __restrict__ wfrag,
    const float* __restrict__ nscsp, const float* __restrict__ tsp,
    float* __restrict__ out)
{
    __shared__ char   Cb8[4][8192];   // slots: pair p = {2p, 2p+1}; [ks][lane]16B
    __shared__ float4 Tls[512];       // 8 KB: [0..255]=nscs, [256..511]=ts (permuted)

    const int tid = threadIdx.x;
    const int lane = tid & 63;
    const int l15 = lane & 15;
    const int g4 = lane >> 4;
    const int w = tid >> 6;                    // 0..3
    const int qb = blockIdx.x * 128 + w * 32;  // 32 rows per wave (2x 16-row tiles)

#define STAGEC(ci, slot) do {                                                      \
        const char* _cs = cfrag8 + (size_t)(ci) * 8192 + w * 2048 + lane * 16;     \
        gload16(_cs,        &Cb8[(slot)][w * 2048]);                               \
        gload16(_cs + 1024, &Cb8[(slot)][w * 2048 + 1024]);                        \
    } while (0)

// S + exp + pack for one chunk (both 16-row tiles); outputs pa0, pa1
#define SEXP(slot, cc, pa0, pa1) do {                                              \
        f32x4 s00 = (f32x4){0.f,0.f,0.f,0.f}, s01 = s00, s10 = s00, s11 = s00;     \
        const char* cb = &Cb8[(slot)][0] + (size_t)lane * 16;                      \
        _Pragma("unroll")                                                          \
        for (int ks = 0; ks < 8; ++ks) {                                           \
            const long2v A = *(const long2v*)(cb + ks * 1024);                     \
            s00 = __builtin_amdgcn_mfma_f32_16x16x32_fp8_fp8(A[0], xq8[0][ks], s00, 0, 0, 0); \
            s10 = __builtin_amdgcn_mfma_f32_16x16x32_fp8_fp8(A[0], xq8[1][ks], s10, 0, 0, 0); \
            s01 = __builtin_amdgcn_mfma_f32_16x16x32_fp8_fp8(A[1], xq8[0][ks], s01, 0, 0, 0); \
            s11 = __builtin_amdgcn_mfma_f32_16x16x32_fp8_fp8(A[1], xq8[1][ks], s11, 0, 0, 0); \
        }                                                                          \
        const int base0 = ((cc) * 2 + 0) * 4 + g4;                                 \
        const int base1 = ((cc) * 2 + 1) * 4 + g4;                                 \
        const float4 q0 = Tls[base0];                                              \
        const float4 t0 = Tls[256 + base0];                                        \
        const float4 q1 = Tls[base1];                                              \
        const float4 t1 = Tls[256 + base1];                                        \
        const float* q0p = (const float*)&q0; const float* t0p = (const float*)&t0;\
        const float* q1p = (const float*)&q1; const float* t1p = (const float*)&t1;\
        float p00[4], p01[4], p10[4], p11[4];                                      \
        _Pragma("unroll")                                                          \
        for (int j = 0; j < 4; ++j) {                                              \
            p00[j] = EXP2(fmaf(t0p[j], s00[j] - hxs0, q0p[j]));                    \
            p01[j] = EXP2(fmaf(t1p[j], s01[j] - hxs0, q1p[j]));                    \
            p10[j] = EXP2(fmaf(t0p[j], s10[j] - hxs1, q0p[j]));                    \
            p11[j] = EXP2(fmaf(t1p[j], s11[j] - hxs1, q1p[j]));                    \
        }                                                                          \
        pa0.u[0] = pack_bf16_trunc(p00[0], p00[1]);                                \
        pa0.u[1] = pack_bf16_trunc(p00[2], p00[3]);                                \
        pa0.u[2] = pack_bf16_trunc(p01[0], p01[1]);                                \
        pa0.u[3] = pack_bf16_trunc(p01[2], p01[3]);                                \
        pa1.u[0] = pack_bf16_trunc(p10[0], p10[1]);                                \
        pa1.u[1] = pack_bf16_trunc(p10[2], p10[3]);                                \
        pa1.u[2] = pack_bf16_trunc(p11[0], p11[1]);                                \
        pa1.u[3] = pack_bf16_trunc(p11[2], p11[3]);                                \
    } while (0)

#define PV(pa0, pa1, wv) do {                                                      \
        _Pragma("unroll")                                                          \
        for (int ot = 0; ot < 8; ++ot) {                                           \
            acc[0][ot] = __builtin_amdgcn_mfma_f32_16x16x32_bf16(pa0.v, wv[ot], acc[0][ot], 0, 0, 0); \
            acc[1][ot] = __builtin_amdgcn_mfma_f32_16x16x32_bf16(pa1.v, wv[ot], acc[1][ot], 0, 0, 0); \
        }                                                                          \
    } while (0)

    // ---- prologue: stage chunks 0,1; tables -> LDS; X -> fp8 regs ----
    STAGEC(0, 0);
    STAGEC(1, 1);

    Tls[tid]       = ((const float4*)nscsp)[tid];
    Tls[256 + tid] = ((const float4*)tsp)[tid];

    long xq8[2][8];
    float xs[2];
    #pragma unroll
    for (int t = 0; t < 2; ++t) {
        const float* xr = x + (size_t)(qb + t * 16 + l15) * 256 + g4 * 8;
        float ss = 0.f;
        #pragma unroll
        for (int ks = 0; ks < 8; ++ks) {
            const float4 a = *(const float4*)(xr + ks * 32);
            const float4 b = *(const float4*)(xr + ks * 32 + 4);
            ss += a.x*a.x + a.y*a.y + a.z*a.z + a.w*a.w
                + b.x*b.x + b.y*b.y + b.z*b.z + b.w*b.w;
            xq8[t][ks] = pack8_e4m3(a, b);
        }
        ss += __shfl_xor(ss, 16, 64);
        ss += __shfl_xor(ss, 32, 64);
        xs[t] = ss;
    }
    const float hxs0 = 0.5f * xs[0];
    const float hxs1 = 0.5f * xs[1];

    f32x4 acc[2][8];
    #pragma unroll
    for (int t = 0; t < 2; ++t)
        #pragma unroll
        for (int ot = 0; ot < 8; ++ot) acc[t][ot] = (f32x4){0.f, 0.f, 0.f, 0.f};

    __syncthreads();   // prologue drain (chunks 0,1 + tables + X)

    const bf16x8* wsrc = (const bf16x8*)wfrag + lane;

    for (int i = 0; i < 16; ++i) {
        const int cA = 2 * i, cB = 2 * i + 1;
        const int sA = (i & 1) * 2, sB = sA + 1;

        // ---- W(cA) -> regs (VMEM pipe; used after S_A+exp_A ~600cy later) ----
        bf16x8 wA[8];
        #pragma unroll
        for (int f = 0; f < 8; ++f) wA[f] = wsrc[(size_t)cA * 512 + f * 64];

        // ---- stage next pair's C (DMA; stays outstanding across W waits) ----
        if (i < 15) {
            STAGEC(cA + 2, sA ^ 2);
            STAGEC(cB + 2, sB ^ 2);
        }

        union { u32 u[4]; bf16x8 v; } paA0, paA1, paB0, paB1;
        SEXP(sA, cA, paA0, paA1);

        // ---- W(cB) -> regs (slack = PV_A + S_B + exp_B) ----
        bf16x8 wB[8];
        #pragma unroll
        for (int f = 0; f < 8; ++f) wB[f] = wsrc[(size_t)cB * 512 + f * 64];

        PV(paA0, paA1, wA);
        SEXP(sB, cB, paB0, paB1);
        PV(paB0, paB1, wB);

        if (i < 15) __syncthreads();   // DMAs had the whole iteration to land
    }

    // ---- epilogue: D layout col=l15 (o-sub), row=g4*4+jr (q-sub) ----
    #pragma unroll
    for (int t = 0; t < 2; ++t) {
        #pragma unroll
        for (int jr = 0; jr < 4; ++jr) {
            const int q = qb + t * 16 + g4 * 4 + jr;
            #pragma unroll
            for (int ot = 0; ot < 8; ++ot)
                out[(size_t)q * 128 + ot * 16 + l15] = acc[t][ot][jr] + bvec[ot * 16 + l15];
        }
    }
#undef STAGEC
#undef SEXP
#undef PV
}

extern "C" void kernel_launch(void* const* d_in, const int* in_sizes, int n_in,
                              void* d_out, int out_size, void* d_ws, size_t ws_size,
                              hipStream_t stream) {
    (void)in_sizes; (void)n_in; (void)out_size; (void)ws_size;
    const float* x       = (const float*)d_in[0];
    const float* centers = (const float*)d_in[1];
    const float* sigmas  = (const float*)d_in[2];
    const float* W       = (const float*)d_in[3];
    const float* b       = (const float*)d_in[4];
    float* out = (float*)d_out;

    char*  cfrag8 = (char*)d_ws;                     // 16384 slots * 16B = 256 KB
    short* wfrag  = (short*)(cfrag8 + 16384 * 16);   // 16384 slots * 16B = 256 KB
    float* nscsp  = (float*)(wfrag + 16384 * 8);     // 4 KB
    float* tsp    = nscsp + 1024;                    // 4 KB

    rbf_prep<<<384, 256, 0, stream>>>(centers, sigmas, W, cfrag8, wfrag, nscsp, tsp);
    rbf_main<<<512, 256, 0, stream>>>(x, b, cfrag8, wfrag, nscsp, tsp, out);
}